// Round 7
// baseline (148.903 us; speedup 1.0000x reference)
//
#include <hip/hip_runtime.h>
#include <stdint.h>

#define M_NODES 2048
#define KSEL 16
#define BATCH 16

typedef unsigned int u32;

// compare-exchange ascending (explicit min/max -> v_min_u32/v_max_u32)
#define CE_ASC(x, y)                    \
  {                                     \
    u32 _a = (x), _b = (y);             \
    (x) = min(_a, _b);                  \
    (y) = max(_a, _b);                  \
  }

// Batcher odd-even mergesort, n=16: 63 CE, ascending. All indices static.
__device__ __forceinline__ void sort16(u32 s[BATCH]) {
#pragma unroll
  for (int p = 1; p < BATCH; p <<= 1) {
#pragma unroll
    for (int k = p; k >= 1; k >>= 1) {
#pragma unroll
      for (int j = k & (p - 1); j + k < BATCH; j += 2 * k) {
#pragma unroll
        for (int i = 0; i < k; ++i) {
          if ((i + j) / (2 * p) == (i + j + k) / (2 * p)) {
            CE_ASC(s[i + j], s[i + j + k])
          }
        }
      }
    }
  }
}

// merge sorted-asc batch s into sorted-asc a (keep 16 smallest of union)
__device__ __forceinline__ void merge_into(u32 a[KSEL], const u32 s[BATCH]) {
#pragma unroll
  for (int i = 0; i < KSEL; ++i) {
    u32 sv = s[KSEL - 1 - i];
    a[i] = min(a[i], sv);  // a becomes bitonic: 16 smallest of union
  }
#pragma unroll
  for (int st = 8; st >= 1; st >>= 1) {  // bitonic clean-up -> ascending
#pragma unroll
    for (int i = 0; i < KSEL; ++i) {
      if ((i & st) == 0) {
        CE_ASC(a[i], a[i + st])
      }
    }
  }
}

// ---- wave-uniform coord load: all lanes read the SAME addresses -> s_load
// (scalar pipe / K$); one batch = 48 dwords held in SGPRs.
__device__ __forceinline__ void load_coords(const float* __restrict__ nodes,
                                            int j0, float cx[BATCH],
                                            float cy[BATCH], float cz[BATCH]) {
  const float* np = nodes + 3 * j0;
#pragma unroll
  for (int u = 0; u < BATCH; ++u) {
    cx[u] = np[3 * u + 0];
    cy[u] = np[3 * u + 1];
    cz[u] = np[3 * u + 2];
  }
}

// keys for one batch: key = (f32bits(d2) & 0xFFFFF800) | j ; positive-float
// bits are order-preserving, low 11 bits = index (ties -> lowest index).
__device__ __forceinline__ void keys_from(float px, float py, float pz,
                                          const float cx[BATCH],
                                          const float cy[BATCH],
                                          const float cz[BATCH], int j0,
                                          u32 s[BATCH]) {
#pragma unroll
  for (int u = 0; u < BATCH; ++u) {
    float dx = px - cx[u], dy = py - cy[u], dz = pz - cz[u];
    float d2 = fmaf(dx, dx, fmaf(dy, dy, dz * dz));  // >= 0 always
    s[u] = (__float_as_uint(d2) & 0xFFFFF800u) | (u32)(j0 + u);
  }
}

// ---- exact top-16 over nodes [jbase, jbase + 16*nbatch), jbase uniform.
// Software-pipelined: load(b+1) -> sort/merge(b) -> keys(b+1), so the
// ~760-cycle sort/merge stretch hides the s_load latency of batch b+1.
__device__ __forceinline__ void select_scalar(float px, float py, float pz,
                                              const float* __restrict__ nodes,
                                              u32 a[KSEL], int jbase,
                                              int nbatch) {
#pragma unroll
  for (int t = 0; t < KSEL; ++t) a[t] = 0xFFFFFFFFu;

  float cx[BATCH], cy[BATCH], cz[BATCH];
  u32 s[BATCH];
  load_coords(nodes, jbase, cx, cy, cz);
  keys_from(px, py, pz, cx, cy, cz, jbase, s);

#pragma unroll 1
  for (int b = 0; b < nbatch - 1; ++b) {
    int j1 = jbase + BATCH * (b + 1);           // wave-uniform
    load_coords(nodes, j1, cx, cy, cz);         // issue s_loads EARLY
    sort16(s);                                  // long VALU stretch
    merge_into(a, s);                           //   hides SMEM latency
    keys_from(px, py, pz, cx, cy, cz, j1, s);   // first use of loads
  }
  sort16(s);
  merge_into(a, s);
}

__device__ __forceinline__ float key_to_dist(u32 k) {
  float v = sqrtf(__uint_as_float(k & 0xFFFFF800u));
  return fmaxf(v, 1e-6f);
}

// ---- kernel 1: block = 64 points x 4 waves; wave w scans nodes [512w,512w+512)
// via scalar loads; partial top-16s merged through small LDS scratch. ----
template <bool STORE>
__global__ __launch_bounds__(256, 4) void k_select(
    const float* __restrict__ means, const float* __restrict__ nodes,
    u32* __restrict__ keys_out, float* __restrict__ sum_ptr, int N) {
  // [3 writer waves][64 lanes][16 keys], row padded to 17 for bank spread
  __shared__ u32 lists[3][64][KSEL + 1];

  int lane = threadIdx.x & 63;
  int w = __builtin_amdgcn_readfirstlane((int)(threadIdx.x >> 6));
  int n = blockIdx.x * 64 + lane;

  float px = means[3 * n + 0];
  float py = means[3 * n + 1];
  float pz = means[3 * n + 2];

  u32 a[KSEL];
  select_scalar(px, py, pz, nodes, a, 512 * w, 512 / BATCH);

  if (w != 0) {
#pragma unroll
    for (int t = 0; t < KSEL; ++t) lists[w - 1][lane][t] = a[t];
  }
  __syncthreads();
  if (w != 0) return;  // waves 1..3 done

  // wave 0: merge the 3 partner lists -> exact global top-16 per point
#pragma unroll 1
  for (int i = 0; i < 3; ++i) {
    u32 b[KSEL];
#pragma unroll
    for (int t = 0; t < KSEL; ++t) b[t] = lists[i][lane][t];
    merge_into(a, b);
  }

  if (STORE) {
    u32* kp = keys_out + (size_t)n * KSEL;
#pragma unroll
    for (int t = 0; t < KSEL; t += 4) {
      *reinterpret_cast<uint4*>(kp + t) =
          make_uint4(a[t], a[t + 1], a[t + 2], a[t + 3]);
    }
  }

  float s = 0.0f;
#pragma unroll
  for (int t = 0; t < KSEL; ++t) s += key_to_dist(a[t]);
#pragma unroll
  for (int off = 32; off > 0; off >>= 1) s += __shfl_xor(s, off);
  if (lane == 0) atomicAdd(sum_ptr, s);
}

// ---- kernel 2: global scale -> softmax -> gather offsets -> output ----
template <bool RELOAD>
__global__ __launch_bounds__(256) void k_finish(
    const float* __restrict__ means, const float* __restrict__ nodes,
    const float* __restrict__ noffs, const int* __restrict__ tptr,
    const u32* __restrict__ keys, const float* __restrict__ sum_ptr,
    float* __restrict__ out, int N) {
  __shared__ float4 so[M_NODES];
  int ti = *tptr;
  {
    const float* src = noffs + (size_t)ti * (3 * M_NODES);
    for (int i = threadIdx.x; i < M_NODES; i += blockDim.x) {
      so[i] = make_float4(src[3 * i + 0], src[3 * i + 1], src[3 * i + 2], 0.0f);
    }
  }
  __syncthreads();

  int n = blockIdx.x * blockDim.x + threadIdx.x;
  float px = means[3 * n + 0];
  float py = means[3 * n + 1];
  float pz = means[3 * n + 2];

  u32 a[KSEL];
  if constexpr (!RELOAD) {
    // fallback (ws too small for key spill): full rescan, scalar path
    select_scalar(px, py, pz, nodes, a, 0, M_NODES / BATCH);
  } else {
    const uint4* kp = reinterpret_cast<const uint4*>(keys + (size_t)n * KSEL);
#pragma unroll
    for (int t = 0; t < 4; ++t) {
      uint4 v = kp[t];
      a[4 * t + 0] = v.x; a[4 * t + 1] = v.y;
      a[4 * t + 2] = v.z; a[4 * t + 3] = v.w;
    }
  }

  float scale = (*sum_ptr) * (1.0f / ((float)N * (float)KSEL)) + 1e-6f;
  float inv = 1.0f / scale;
  float vmin = key_to_dist(a[0]);  // a[] sorted ascending -> a[0] is min

  float wsum = 0.0f, mx = 0.0f, my = 0.0f, mz = 0.0f;
#pragma unroll
  for (int t = 0; t < KSEL; ++t) {
    u32 k = a[t];
    float v = key_to_dist(k);
    float e = __expf((vmin - v) * inv);  // softmax(-v/scale), max-shifted
    float4 o = so[k & 0x7FFu];
    wsum += e;
    mx = fmaf(e, o.x, mx);
    my = fmaf(e, o.y, my);
    mz = fmaf(e, o.z, mz);
  }
  float r = 1.0f / wsum;
  out[3 * n + 0] = px + mx * r;
  out[3 * n + 1] = py + my * r;
  out[3 * n + 2] = pz + mz * r;
}

extern "C" void kernel_launch(void* const* d_in, const int* in_sizes, int n_in,
                              void* d_out, int out_size, void* d_ws,
                              size_t ws_size, hipStream_t stream) {
  const float* means = (const float*)d_in[0];
  const float* nodes = (const float*)d_in[1];
  const float* noffs = (const float*)d_in[2];
  const int* tptr = (const int*)d_in[3];
  int N = in_sizes[0] / 3;  // 131072

  float* sum_ptr = (float*)d_ws;
  u32* keys = (u32*)((char*)d_ws + 256);
  size_t need = 256 + (size_t)N * KSEL * sizeof(u32);

  size_t zbytes = ws_size < 256 ? ws_size : 256;
  if (zbytes) hipMemsetAsync(d_ws, 0, zbytes, stream);

  dim3 blk(256);
  dim3 grid_sel((unsigned)((N + 63) / 64));     // 64 points per block
  dim3 grid_fin((unsigned)((N + 255) / 256));
  float* out = (float*)d_out;

  if (ws_size >= need) {
    k_select<true><<<grid_sel, blk, 0, stream>>>(means, nodes, keys, sum_ptr, N);
    k_finish<true><<<grid_fin, blk, 0, stream>>>(means, nodes, noffs, tptr,
                                                 keys, sum_ptr, out, N);
  } else {
    // ws too small to spill keys: recompute selection in kernel 2
    k_select<false><<<grid_sel, blk, 0, stream>>>(means, nodes, nullptr,
                                                  sum_ptr, N);
    k_finish<false><<<grid_fin, blk, 0, stream>>>(means, nodes, noffs, tptr,
                                                  keys, sum_ptr, out, N);
  }
}

// Round 8
// 129.279 us; speedup vs baseline: 1.1518x; 1.1518x over previous
//
#include <hip/hip_runtime.h>
#include <stdint.h>

#define M_NODES 2048
#define KSEL 16
#define BATCH 16

typedef unsigned int u32;

// compare-exchange ascending (explicit min/max -> v_min_u32/v_max_u32)
#define CE_ASC(x, y)                    \
  {                                     \
    u32 _a = (x), _b = (y);             \
    (x) = min(_a, _b);                  \
    (y) = max(_a, _b);                  \
  }

// Batcher odd-even mergesort, n=16: 63 CE, ascending. All indices static.
__device__ __forceinline__ void sort16(u32 s[BATCH]) {
#pragma unroll
  for (int p = 1; p < BATCH; p <<= 1) {
#pragma unroll
    for (int k = p; k >= 1; k >>= 1) {
#pragma unroll
      for (int j = k & (p - 1); j + k < BATCH; j += 2 * k) {
#pragma unroll
        for (int i = 0; i < k; ++i) {
          if ((i + j) / (2 * p) == (i + j + k) / (2 * p)) {
            CE_ASC(s[i + j], s[i + j + k])
          }
        }
      }
    }
  }
}

// merge sorted-asc batch s into sorted-asc a (keep 16 smallest of union)
__device__ __forceinline__ void merge_into(u32 a[KSEL], const u32 s[BATCH]) {
#pragma unroll
  for (int i = 0; i < KSEL; ++i) {
    u32 sv = s[KSEL - 1 - i];
    a[i] = min(a[i], sv);  // a becomes bitonic: 16 smallest of union
  }
#pragma unroll
  for (int st = 8; st >= 1; st >>= 1) {  // bitonic clean-up -> ascending
#pragma unroll
    for (int i = 0; i < KSEL; ++i) {
      if ((i & st) == 0) {
        CE_ASC(a[i], a[i + st])
      }
    }
  }
}

// ---- exact top-16 over nodes [jbase, jbase + 16*nbatch), jbase uniform ----
// All lanes process the SAME node j each step -> node coords are wave-uniform
// -> compiler emits s_load (scalar pipe, no LDS / no per-lane VMEM).
// key = (f32bits(d2) & 0xFFFFF800) | j ; positive-float bits are order-
// preserving, low 11 bits = index (ties -> lowest index, like top_k).
__device__ __forceinline__ void select_scalar(float px, float py, float pz,
                                              const float* __restrict__ nodes,
                                              u32 a[KSEL], int jbase,
                                              int nbatch) {
#pragma unroll
  for (int t = 0; t < KSEL; ++t) a[t] = 0xFFFFFFFFu;

#pragma unroll 1
  for (int b = 0; b < nbatch; ++b) {
    int j0 = jbase + BATCH * b;                  // wave-uniform
    const float* np = nodes + 3 * j0;
    u32 s[BATCH];
#pragma unroll
    for (int u = 0; u < BATCH; ++u) {
      float nx = np[3 * u + 0];                  // uniform -> SGPR
      float ny = np[3 * u + 1];
      float nz = np[3 * u + 2];
      float dx = px - nx, dy = py - ny, dz = pz - nz;
      float d2 = fmaf(dx, dx, fmaf(dy, dy, dz * dz));  // >= 0 always
      s[u] = (__float_as_uint(d2) & 0xFFFFF800u) | (u32)(j0 + u);
    }
    sort16(s);
    merge_into(a, s);
  }
}

__device__ __forceinline__ float key_to_dist(u32 k) {
  float v = sqrtf(__uint_as_float(k & 0xFFFFF800u));
  return fmaxf(v, 1e-6f);
}

// ---- kernel 1: block = 64 points x 4 waves; wave w scans nodes [512w,512w+512)
// via scalar loads; partial top-16s merged through small LDS scratch. ----
template <bool STORE>
__global__ __launch_bounds__(256, 8) void k_select(
    const float* __restrict__ means, const float* __restrict__ nodes,
    u32* __restrict__ keys_out, float* __restrict__ sum_ptr, int N) {
  // [3 writer waves][64 lanes][16 keys], row padded to 17 for bank spread
  __shared__ u32 lists[3][64][KSEL + 1];

  int lane = threadIdx.x & 63;
  int w = __builtin_amdgcn_readfirstlane((int)(threadIdx.x >> 6));
  int n = blockIdx.x * 64 + lane;

  float px = means[3 * n + 0];
  float py = means[3 * n + 1];
  float pz = means[3 * n + 2];

  // ---- convoy breaker: one-time per-wave phase stagger (0..7 x 128 cyc).
  // All 8 waves/SIMD otherwise run identical instruction streams and hit
  // their per-batch s_waitcnt lgkmcnt in lock-step; staggering spreads the
  // SMEM waits across the ~670-cyc batch period so TLP can cover them.
  {
    int phase = (int)(((blockIdx.x >> 8) + ((u32)w << 1)) & 7);  // uniform
#pragma unroll 1
    for (int i = 0; i < phase; ++i) __builtin_amdgcn_s_sleep(2);
  }

  u32 a[KSEL];
  select_scalar(px, py, pz, nodes, a, 512 * w, 512 / BATCH);

  if (w != 0) {
#pragma unroll
    for (int t = 0; t < KSEL; ++t) lists[w - 1][lane][t] = a[t];
  }
  __syncthreads();
  if (w != 0) return;  // waves 1..3 done

  // wave 0: merge the 3 partner lists -> exact global top-16 per point
#pragma unroll 1
  for (int i = 0; i < 3; ++i) {
    u32 b[KSEL];
#pragma unroll
    for (int t = 0; t < KSEL; ++t) b[t] = lists[i][lane][t];
    merge_into(a, b);
  }

  if (STORE) {
    u32* kp = keys_out + (size_t)n * KSEL;
#pragma unroll
    for (int t = 0; t < KSEL; t += 4) {
      *reinterpret_cast<uint4*>(kp + t) =
          make_uint4(a[t], a[t + 1], a[t + 2], a[t + 3]);
    }
  }

  float s = 0.0f;
#pragma unroll
  for (int t = 0; t < KSEL; ++t) s += key_to_dist(a[t]);
#pragma unroll
  for (int off = 32; off > 0; off >>= 1) s += __shfl_xor(s, off);
  if (lane == 0) atomicAdd(sum_ptr, s);
}

// ---- kernel 2: global scale -> softmax -> gather offsets -> output ----
template <bool RELOAD>
__global__ __launch_bounds__(256) void k_finish(
    const float* __restrict__ means, const float* __restrict__ nodes,
    const float* __restrict__ noffs, const int* __restrict__ tptr,
    const u32* __restrict__ keys, const float* __restrict__ sum_ptr,
    float* __restrict__ out, int N) {
  __shared__ float4 so[M_NODES];
  int ti = *tptr;
  {
    const float* src = noffs + (size_t)ti * (3 * M_NODES);
    for (int i = threadIdx.x; i < M_NODES; i += blockDim.x) {
      so[i] = make_float4(src[3 * i + 0], src[3 * i + 1], src[3 * i + 2], 0.0f);
    }
  }
  __syncthreads();

  int n = blockIdx.x * blockDim.x + threadIdx.x;
  float px = means[3 * n + 0];
  float py = means[3 * n + 1];
  float pz = means[3 * n + 2];

  u32 a[KSEL];
  if constexpr (!RELOAD) {
    // fallback (ws too small for key spill): full rescan, scalar path
    select_scalar(px, py, pz, nodes, a, 0, M_NODES / BATCH);
  } else {
    const uint4* kp = reinterpret_cast<const uint4*>(keys + (size_t)n * KSEL);
#pragma unroll
    for (int t = 0; t < 4; ++t) {
      uint4 v = kp[t];
      a[4 * t + 0] = v.x; a[4 * t + 1] = v.y;
      a[4 * t + 2] = v.z; a[4 * t + 3] = v.w;
    }
  }

  float scale = (*sum_ptr) * (1.0f / ((float)N * (float)KSEL)) + 1e-6f;
  float inv = 1.0f / scale;
  float vmin = key_to_dist(a[0]);  // a[] sorted ascending -> a[0] is min

  float wsum = 0.0f, mx = 0.0f, my = 0.0f, mz = 0.0f;
#pragma unroll
  for (int t = 0; t < KSEL; ++t) {
    u32 k = a[t];
    float v = key_to_dist(k);
    float e = __expf((vmin - v) * inv);  // softmax(-v/scale), max-shifted
    float4 o = so[k & 0x7FFu];
    wsum += e;
    mx = fmaf(e, o.x, mx);
    my = fmaf(e, o.y, my);
    mz = fmaf(e, o.z, mz);
  }
  float r = 1.0f / wsum;
  out[3 * n + 0] = px + mx * r;
  out[3 * n + 1] = py + my * r;
  out[3 * n + 2] = pz + mz * r;
}

extern "C" void kernel_launch(void* const* d_in, const int* in_sizes, int n_in,
                              void* d_out, int out_size, void* d_ws,
                              size_t ws_size, hipStream_t stream) {
  const float* means = (const float*)d_in[0];
  const float* nodes = (const float*)d_in[1];
  const float* noffs = (const float*)d_in[2];
  const int* tptr = (const int*)d_in[3];
  int N = in_sizes[0] / 3;  // 131072

  float* sum_ptr = (float*)d_ws;
  u32* keys = (u32*)((char*)d_ws + 256);
  size_t need = 256 + (size_t)N * KSEL * sizeof(u32);

  size_t zbytes = ws_size < 256 ? ws_size : 256;
  if (zbytes) hipMemsetAsync(d_ws, 0, zbytes, stream);

  dim3 blk(256);
  dim3 grid_sel((unsigned)((N + 63) / 64));     // 64 points per block
  dim3 grid_fin((unsigned)((N + 255) / 256));
  float* out = (float*)d_out;

  if (ws_size >= need) {
    k_select<true><<<grid_sel, blk, 0, stream>>>(means, nodes, keys, sum_ptr, N);
    k_finish<true><<<grid_fin, blk, 0, stream>>>(means, nodes, noffs, tptr,
                                                 keys, sum_ptr, out, N);
  } else {
    // ws too small to spill keys: recompute selection in kernel 2
    k_select<false><<<grid_sel, blk, 0, stream>>>(means, nodes, nullptr,
                                                  sum_ptr, N);
    k_finish<false><<<grid_fin, blk, 0, stream>>>(means, nodes, noffs, tptr,
                                                  keys, sum_ptr, out, N);
  }
}